// Round 9
// baseline (206.083 us; speedup 1.0000x reference)
//
#include <hip/hip_runtime.h>
#include <math.h>

#define BB 1024
#define SS 50
#define SSP 51          // padded LDS row stride for shT
#define HH 128
#define KK 4
#define VV 100000
#define NVT8 800        // v-tiles padded: 100/XCD = 25 quads/XCD (int!)
#define VPAD (NVT8*128) // 102400 zero-padded emb rows
#define KS (KK*SS)      // 200
#define NHM 400         // h-MFMA blocks (128 rows each)
#define NPAD_ALL 2400.0f // zero pad rows ALL scored: VPAD-VV, exp(0)=1 each
#define CONVB 2048      // grid-stride conv blocks (merged into route1)
#define LOG2E 1.44269504f
#define SGRID ((NVT8/4)*8)  // 1600: 16-wave block, FOUR 128v x 128b tiles

typedef __attribute__((ext_vector_type(8))) short bf16x8;
typedef __attribute__((ext_vector_type(4))) float f32x4;

__device__ __forceinline__ ushort f2bf(float x) {
  unsigned u = __float_as_uint(x);
  unsigned r = u + 0x7FFF + ((u >> 16) & 1);   // round-to-nearest-even
  return (ushort)(r >> 16);
}
__device__ __forceinline__ float bf2f(ushort u) {
  return __uint_as_float(((unsigned)u) << 16);
}
__device__ __forceinline__ bf16x8 cvt8(float4 a, float4 b) {
  bf16x8 r;
  r[0] = (short)f2bf(a.x); r[1] = (short)f2bf(a.y);
  r[2] = (short)f2bf(a.z); r[3] = (short)f2bf(a.w);
  r[4] = (short)f2bf(b.x); r[5] = (short)f2bf(b.y);
  r[6] = (short)f2bf(b.z); r[7] = (short)f2bf(b.w);
  return r;
}

// ---- fused pre-pass ------------------------------------------------------
// blocks [0,NHM): h = seq_emb @ W^T via bf16 MFMA -> hb16
// blocks [NHM,NHM+KS): cw0 column exp-sums + zero s1/s2/accum (8 replicas)
__global__ __launch_bounds__(256) void k_pre(const float* __restrict__ emb,
                                             const float* __restrict__ cw0,
                                             float* __restrict__ cm,
                                             float* __restrict__ s1,
                                             float* __restrict__ s2,
                                             float* __restrict__ accum,
                                             const int* __restrict__ item_seq,
                                             const float* __restrict__ W,
                                             ushort* __restrict__ hb16) {
  const int t = threadIdx.x;
  if (blockIdx.x < NHM) {
    __shared__ __align__(16) ushort sWf[32 * 512];   // W bf16 fragments, 32 KB
    const int w = t >> 6;
    const int lane = t & 63;
    const int lr = lane & 15;
    const int lq = lane >> 4;
    const int m0 = blockIdx.x * 128;

#pragma unroll
    for (int it = 0; it < 8; ++it) {
      int pos = t + it * 256;
      int ch = pos >> 6, l = pos & 63;
      int n = (ch & 7) * 16 + (l & 15);
      int k0 = (ch >> 3) * 32 + (l >> 4) * 8;
      float4 a = *(const float4*)&W[n * HH + k0];
      float4 b = *(const float4*)&W[n * HH + k0 + 4];
      *(bf16x8*)&sWf[ch * 512 + l * 8] = cvt8(a, b);
    }

    bf16x8 af[4][2];
#pragma unroll
    for (int vv = 0; vv < 2; ++vv) {
      int m = m0 + w * 32 + vv * 16 + lr;
      int idx = item_seq[m];
#pragma unroll
      for (int ks = 0; ks < 4; ++ks) {
        if (idx != 0) {
          float4 a = *(const float4*)&emb[(size_t)idx * HH + ks * 32 + lq * 8];
          float4 b = *(const float4*)&emb[(size_t)idx * HH + ks * 32 + lq * 8 + 4];
          af[ks][vv] = cvt8(a, b);
        } else {
          af[ks][vv] = (bf16x8){0, 0, 0, 0, 0, 0, 0, 0};
        }
      }
    }
    __syncthreads();

    f32x4 acc[8][2];
#pragma unroll
    for (int nt = 0; nt < 8; ++nt)
#pragma unroll
      for (int vv = 0; vv < 2; ++vv) acc[nt][vv] = (f32x4){0.f, 0.f, 0.f, 0.f};

#pragma unroll
    for (int ks = 0; ks < 4; ++ks) {
      bf16x8 bw[8];
#pragma unroll
      for (int nt = 0; nt < 8; ++nt)
        bw[nt] = *(const bf16x8*)&sWf[(ks * 8 + nt) * 512 + lane * 8];
#pragma unroll
      for (int nt = 0; nt < 8; ++nt)
#pragma unroll
        for (int vv = 0; vv < 2; ++vv)
          acc[nt][vv] = __builtin_amdgcn_mfma_f32_16x16x32_bf16(af[ks][vv], bw[nt], acc[nt][vv], 0, 0, 0);
    }

#pragma unroll
    for (int nt = 0; nt < 8; ++nt)
#pragma unroll
      for (int vv = 0; vv < 2; ++vv)
#pragma unroll
        for (int r = 0; r < 4; ++r) {
          int m = m0 + w * 32 + vv * 16 + lq * 4 + r;
          hb16[(size_t)m * HH + nt * 16 + lr] = f2bf(acc[nt][vv][r]);
        }
  } else {
    __shared__ float red[256];
    const int c = blockIdx.x - NHM;
    if (t < 8) s1[t * KS + c] = 0.f;
    if (t >= 8 && t < 16) s2[(t - 8) * KS + c] = 0.f;
    if (c < 32) accum[c * 256 + t] = 0.f;   // zero all 8 replicas (8*1024)
    float s = 0.f;
    for (int b = t; b < BB; b += 256) s += __expf(cw0[(size_t)b * KS + c]);
    red[t] = s;
    __syncthreads();
    for (int o = 128; o > 0; o >>= 1) {
      if (t < o) red[t] += red[t + o];
      __syncthreads();
    }
    if (t == 0) cm[c] = red[0];
  }
}

// ---------------- routing: per-batch step (h LDS-staged, bf16) ------------
// R6 form restored: per-b blocks for ALL 3 iterations (R8's per-(b,k) split
// measured +4 us — refuted). 3 separate launches = the grid barrier.
// Launch 1 carries CONVB extra blocks (>= BB) doing the emb->bf16 conv.
__global__ __launch_bounds__(256) void k_route(const float* __restrict__ cwsrc,
                                               float* __restrict__ cwdst,
                                               const ushort* __restrict__ hb16,
                                               const float* __restrict__ csum,
                                               int nslots,
                                               const float* __restrict__ mask,
                                               int last,
                                               float* __restrict__ out_ue,
                                               const float* __restrict__ emb,
                                               const int* __restrict__ item,
                                               ushort* __restrict__ bestb,
                                               float* __restrict__ csnext,
                                               float* __restrict__ si,
                                               ushort* __restrict__ embb) {
  const int t = threadIdx.x;
  if (blockIdx.x >= BB) {
    // emb -> bf16 (zero-pad tail to VPAD rows), grid-strided (route1 only)
    const size_t stride = (size_t)CONVB * 256 * 4;
    for (size_t i = ((size_t)(blockIdx.x - BB) * 256 + t) * 4;
         i < (size_t)VPAD * HH; i += stride) {
      ushort4 o;
      if (i < (size_t)VV * HH) {
        float4 v = *(const float4*)&emb[i];
        o = make_ushort4(f2bf(v.x), f2bf(v.y), f2bf(v.z), f2bf(v.w));
      } else {
        o = make_ushort4(0, 0, 0, 0);
      }
      *(ushort4*)&embb[i] = o;
    }
    return;
  }

  __shared__ ushort shT[128 * SSP];   // [col][s] transposed h, 13 KB
  __shared__ float swl[KS];
  __shared__ float c32p[256];
  __shared__ float c32[128];
  __shared__ float csq[128];
  __shared__ float ie4r[32];
  __shared__ float ie4z[32];
  __shared__ float fac[4];
  __shared__ float cosk[4];
  __shared__ float cosr[4];
  __shared__ int kb;
  const int b = blockIdx.x;

  for (int p = t; p < (SS * HH) / 4; p += 256) {
    int flat = 4 * p;
    int s = flat >> 7, col = flat & 127;
    ushort4 v = *(const ushort4*)&hb16[(size_t)b * SS * HH + flat];
    shT[(col + 0) * SSP + s] = v.x;
    shT[(col + 1) * SSP + s] = v.y;
    shT[(col + 2) * SSP + s] = v.z;
    shT[(col + 3) * SSP + s] = v.w;
  }
  if (t < KS) {
    float den = 0.f;
    for (int g2 = 0; g2 < nslots; ++g2) den += csum[g2 * KS + t];
    float v = __expf(cwsrc[(size_t)b * KS + t]) / den;
    if (mask[b * SS + (t % SS)] == 0.0f) v = 0.0f;
    swl[t] = v;
  }
  __syncthreads();

  {  // c32: col = t&127, s-half = t>>7 (25 each)
    int col = t & 127;
    int half = t >> 7;
    int k = col >> 5;
    float acc = 0.f;
    const float* swk = &swl[k * SS + half * 25];
    const ushort* hc = &shT[col * SSP + half * 25];
    for (int s = 0; s < 25; ++s) acc += swk[s] * bf2f(hc[s]);
    c32p[t] = acc;
  }
  __syncthreads();
  if (t < 128) c32[t] = c32p[t] + c32p[t + 128];
  __syncthreads();
  if (t < 4) {
    float nrm = 0.f;
#pragma unroll
    for (int j = 0; j < 32; ++j) { float c = c32[32 * t + j]; nrm += c * c; }
    nrm *= 4.0f;
    fac[t] = nrm / (1.0f + nrm) / sqrtf(nrm + 1e-9f);
  }
  __syncthreads();
  if (t < 128) csq[t] = c32[t] * fac[t >> 5];
  __syncthreads();

  if (!last) {
    if (t < KS) {
      int k = t / SS, s = t % SS;
      const float* cq = &csq[32 * k];
      float d = 0.f;
#pragma unroll
      for (int j = 0; j < 32; ++j) d += bf2f(shT[(32 * k + j) * SSP + s]) * cq[j];
      float nv = cwsrc[(size_t)b * KS + t] + 4.0f * d;
      cwdst[(size_t)b * KS + t] = nv;
      atomicAdd(&csnext[(b & 7) * KS + t], __expf(nv));
    }
  } else {
    for (int hh = t; hh < 512; hh += 256) {
      int k = hh >> 7, r = (hh & 127) >> 2;
      out_ue[(size_t)b * 512 + hh] = csq[32 * k + r];
    }
    if (t < 32) {
      int idx = item[b];
      const float* e = emb + (size_t)idx * HH + 4 * t;
      float v = e[0] + e[1] + e[2] + e[3];   // raw emb row (scores use raw emb)
      ie4r[t] = v;
      ie4z[t] = (idx == 0) ? 0.f : v;        // zeroed lookup (cos path)
    }
    __syncthreads();
    if (t < 4) {
      float cz = 0.f, cr = 0.f;
#pragma unroll
      for (int j = 0; j < 32; ++j) {
        cz += csq[32 * t + j] * ie4z[j];
        cr += csq[32 * t + j] * ie4r[j];
      }
      cosk[t] = cz; cosr[t] = cr;
    }
    __syncthreads();
    if (t == 0) {
      int kbest = 0; float bv = cosk[0];
#pragma unroll
      for (int k = 1; k < 4; ++k) if (cosk[k] > bv) { bv = cosk[k]; kbest = k; }
      kb = kbest;
      si[b] = cosr[kbest];
    }
    __syncthreads();
    // pre-scale by log2(e): scoring epilogue then uses exp2 (single v_exp_f32)
    if (t < 128) bestb[(size_t)b * HH + t] = f2bf(csq[32 * kb + (t >> 2)] * LOG2E);
  }
}

// ---------------- scoring: v8 = v7 geometry, 16-wave 4-tile block ---------
// Ladder: v1=54.2 (1 tile, 4w) -> v5=53.2 (async stage) -> v7=49-50
// (2 tiles, 8w, one drain). v8: same per-wave register geometry (the thing
// v2/v3/v4 broke and paid 25-45 us for), FOUR tiles per 16-wave block:
// one drain per 4 tiles, staging 2 chunks/wave, wave-slot residency limit
// 2 blocks x 16 waves = 32 waves/CU. NVT8 784->800 so quads/XCD is integer
// (25); pad rows are zeros -> exp2(0)=1 each -> NPAD_ALL=2400.
__global__ __launch_bounds__(1024) void k_score_mfma(const ushort* __restrict__ bestb,
                                                     const ushort* __restrict__ embb,
                                                     float* __restrict__ accum) {
  const int lin = blockIdx.x;
  const int xcd = lin & 7;          // same-xcd blocks share an embb slice (L2)
  const int g = lin >> 3;           // 0..199
  const int bt8 = g & 7;            // b strip (128 rows)
  const int vt0 = xcd * 100 + (g >> 3) * 4;   // quad base, g>>3 in 0..24

  __shared__ __align__(16) ushort sB[32 * 512];   // 32 KB
  __shared__ float ssm[128][16];                  // 8 KB
  const int t = threadIdx.x;
  const int w = t >> 6;             // 0..15
  const int lane = t & 63;
  const int lr = lane & 15;
  const int lq = lane >> 4;
  const int b0 = bt8 * 128;
  const int tile = w >> 2;          // which v-tile of the quad (0..3)
  const int ws = w & 3;             // wave-sub within tile (v5's w)
  const int v0 = (vt0 + tile) * 128 + ws * 32;

  // emb fragments (per-wave unique), hoisted: 32 VGPRs in flight
  bf16x8 af[4][2];
#pragma unroll
  for (int ks = 0; ks < 4; ++ks)
#pragma unroll
    for (int vv = 0; vv < 2; ++vv)
      af[ks][vv] = *(const bf16x8*)&embb[(size_t)(v0 + vv * 16 + lr) * HH + ks * 32 + lq * 8];

  // stage bestb strip direct to LDS (async): 32 chunks over 16 waves.
#pragma unroll
  for (int it = 0; it < 2; ++it) {
    int ch = w + it * 16;
    int ks = ch >> 3, bt = ch & 7;
    const ushort* src = &bestb[(size_t)(b0 + bt * 16 + lr) * HH + ks * 32 + lq * 8];
    __builtin_amdgcn_global_load_lds(
        (const __attribute__((address_space(1))) unsigned int*)src,
        (__attribute__((address_space(3))) unsigned int*)&sB[ch * 512 + lane * 8],
        16, 0, 0);
  }

  f32x4 acc[8][2];
#pragma unroll
  for (int bt = 0; bt < 8; ++bt)
#pragma unroll
    for (int vv = 0; vv < 2; ++vv) acc[bt][vv] = (f32x4){0.f, 0.f, 0.f, 0.f};

  __syncthreads();   // one vmcnt drain for 4 tiles' worth of compute

  bf16x8 bcur[8];
#pragma unroll
  for (int bt = 0; bt < 8; ++bt)
    bcur[bt] = *(const bf16x8*)&sB[bt * 512 + lane * 8];

#pragma unroll
  for (int ks = 0; ks < 4; ++ks) {
    bf16x8 bnxt[8];
    if (ks < 3) {
#pragma unroll
      for (int bt = 0; bt < 8; ++bt)
        bnxt[bt] = *(const bf16x8*)&sB[((ks + 1) * 8 + bt) * 512 + lane * 8];
    }
#pragma unroll
    for (int bt = 0; bt < 8; ++bt)
#pragma unroll
      for (int vv = 0; vv < 2; ++vv)
        acc[bt][vv] = __builtin_amdgcn_mfma_f32_16x16x32_bf16(af[ks][vv], bcur[bt], acc[bt][vv], 0, 0, 0);
    if (ks < 3) {
#pragma unroll
      for (int bt = 0; bt < 8; ++bt) bcur[bt] = bnxt[bt];
    }
  }

  // epilogue: scores pre-scaled by log2(e) -> single v_exp_f32 each
#pragma unroll
  for (int bt = 0; bt < 8; ++bt) {
    float e[8];
#pragma unroll
    for (int vv = 0; vv < 2; ++vv)
#pragma unroll
      for (int r = 0; r < 4; ++r)
        e[vv * 4 + r] = __builtin_amdgcn_exp2f(acc[bt][vv][r]);
#pragma unroll
    for (int o = 4; o > 0; o >>= 1)
#pragma unroll
      for (int j = 0; j < 8; ++j)
        if (j < o) e[j] += e[j + o];
    float s = e[0];
    s += __shfl_xor(s, 16);
    s += __shfl_xor(s, 32);
    if (lq == 0) ssm[bt * 16 + lr][w] = s;
  }
  __syncthreads();
  if (t < 128) {
    float s = 0.f;
#pragma unroll
    for (int r = 0; r < 16; ++r) s += ssm[t][r];
    atomicAdd(&accum[(size_t)(lin & 7) * BB + b0 + t], s);
  }
}

// ---------------- final loss: one block -----------------------------------
__global__ __launch_bounds__(256) void k_loss(const float* __restrict__ accum,
                                              const float* __restrict__ si,
                                              float* __restrict__ outloss) {
  __shared__ float red[256];
  const int t = threadIdx.x;
  float s = 0.f;
  for (int b = t; b < BB; b += 256) {
    float a = 0.f;
#pragma unroll
    for (int r = 0; r < 8; ++r) a += accum[(size_t)r * BB + b];
    s += logf(a - NPAD_ALL) - si[b];   // no max: scores ~[-0.5,0.5]
  }
  red[t] = s;
  __syncthreads();
  for (int o = 128; o > 0; o >>= 1) {
    if (t < o) red[t] += red[t + o];
    __syncthreads();
  }
  if (t == 0) outloss[0] = red[0] / (float)BB;
}

extern "C" void kernel_launch(void* const* d_in, const int* in_sizes, int n_in,
                              void* d_out, int out_size, void* d_ws, size_t ws_size,
                              hipStream_t stream) {
  const int*   item_seq = (const int*)d_in[0];
  const float* mask     = (const float*)d_in[1];
  const int*   item     = (const int*)d_in[2];
  const float* emb      = (const float*)d_in[3];
  const float* W        = (const float*)d_in[4];
  const float* cw0      = (const float*)d_in[5];
  float* out = (float*)d_out;
  float* outloss = out + (size_t)BB * KK * HH;

  float* ws = (float*)d_ws;
  float* cm    = ws;                                 // KS (rounded 256)
  float* s1    = cm + 256;                           // 8*200
  float* s2    = s1 + 8 * KS;                        // 8*200
  float* si    = s2 + 8 * KS;                        // B
  float* accum = si + BB;                            // 8*B (replicated)
  float* cw    = accum + 8 * BB;                     // B*K*S
  ushort* hb16  = (ushort*)(cw + (size_t)BB * KS);   // B*S*H bf16
  ushort* embb  = hb16 + (size_t)BB * SS * HH;       // VPAD*H bf16
  ushort* bestb = embb + (size_t)VPAD * HH;          // B*H bf16

  k_pre<<<dim3(NHM + KS), 256, 0, stream>>>(emb, cw0, cm, s1, s2, accum,
                                            item_seq, W, hb16);

  k_route<<<dim3(BB + CONVB), 256, 0, stream>>>(cw0, cw, hb16, cm, 1, mask, 0, out, emb, item, bestb, s1, si, embb);
  k_route<<<dim3(BB), 256, 0, stream>>>(cw, cw, hb16, s1, 8, mask, 0, out, emb, item, bestb, s2, si, embb);
  k_route<<<dim3(BB), 256, 0, stream>>>(cw, cw, hb16, s2, 8, mask, 1, out, emb, item, bestb, s1, si, embb);

  k_score_mfma<<<dim3(SGRID), 1024, 0, stream>>>(bestb, embb, accum);
  k_loss<<<dim3(1), 256, 0, stream>>>(accum, si, outloss);
}

// Round 11
// 196.499 us; speedup vs baseline: 1.0488x; 1.0488x over previous
//
#include <hip/hip_runtime.h>
#include <math.h>

#define BB 1024
#define SS 50
#define SSP 51          // padded LDS row stride for shT
#define HH 128
#define KK 4
#define VV 100000
#define NVT8 784        // v-tiles padded to 98/XCD = 14 chunks x 7
#define VPAD (NVT8*128) // 100352 zero-padded emb rows
#define KS (KK*SS)      // 200
#define NHM 400         // h-MFMA blocks (128 rows each)
#define NPAD_ALL 352.0f // zero pad rows ALL scored: VPAD-VV, exp(0)=1 each
#define CONVB 2048      // grid-stride conv blocks (merged into route1)
#define LOG2E 1.44269504f
#define SVPB 7          // tiles per chain
#define SNCH 14         // chains per (xcd, bstrip)
#define SGRID (8*8*SNCH) // 896

typedef __attribute__((ext_vector_type(8))) short bf16x8;
typedef __attribute__((ext_vector_type(4))) float f32x4;

__device__ __forceinline__ ushort f2bf(float x) {
  unsigned u = __float_as_uint(x);
  unsigned r = u + 0x7FFF + ((u >> 16) & 1);   // round-to-nearest-even
  return (ushort)(r >> 16);
}
__device__ __forceinline__ float bf2f(ushort u) {
  return __uint_as_float(((unsigned)u) << 16);
}
__device__ __forceinline__ bf16x8 cvt8(float4 a, float4 b) {
  bf16x8 r;
  r[0] = (short)f2bf(a.x); r[1] = (short)f2bf(a.y);
  r[2] = (short)f2bf(a.z); r[3] = (short)f2bf(a.w);
  r[4] = (short)f2bf(b.x); r[5] = (short)f2bf(b.y);
  r[6] = (short)f2bf(b.z); r[7] = (short)f2bf(b.w);
  return r;
}

// ---- fused pre-pass ------------------------------------------------------
// blocks [0,NHM): h = seq_emb @ W^T via bf16 MFMA -> hb16
// blocks [NHM,NHM+KS): cw0 column exp-sums + zero s1/s2/accum (8 replicas)
__global__ __launch_bounds__(256) void k_pre(const float* __restrict__ emb,
                                             const float* __restrict__ cw0,
                                             float* __restrict__ cm,
                                             float* __restrict__ s1,
                                             float* __restrict__ s2,
                                             float* __restrict__ accum,
                                             const int* __restrict__ item_seq,
                                             const float* __restrict__ W,
                                             ushort* __restrict__ hb16) {
  const int t = threadIdx.x;
  if (blockIdx.x < NHM) {
    __shared__ __align__(16) ushort sWf[32 * 512];   // W bf16 fragments, 32 KB
    const int w = t >> 6;
    const int lane = t & 63;
    const int lr = lane & 15;
    const int lq = lane >> 4;
    const int m0 = blockIdx.x * 128;

#pragma unroll
    for (int it = 0; it < 8; ++it) {
      int pos = t + it * 256;
      int ch = pos >> 6, l = pos & 63;
      int n = (ch & 7) * 16 + (l & 15);
      int k0 = (ch >> 3) * 32 + (l >> 4) * 8;
      float4 a = *(const float4*)&W[n * HH + k0];
      float4 b = *(const float4*)&W[n * HH + k0 + 4];
      *(bf16x8*)&sWf[ch * 512 + l * 8] = cvt8(a, b);
    }

    bf16x8 af[4][2];
#pragma unroll
    for (int vv = 0; vv < 2; ++vv) {
      int m = m0 + w * 32 + vv * 16 + lr;
      int idx = item_seq[m];
#pragma unroll
      for (int ks = 0; ks < 4; ++ks) {
        if (idx != 0) {
          float4 a = *(const float4*)&emb[(size_t)idx * HH + ks * 32 + lq * 8];
          float4 b = *(const float4*)&emb[(size_t)idx * HH + ks * 32 + lq * 8 + 4];
          af[ks][vv] = cvt8(a, b);
        } else {
          af[ks][vv] = (bf16x8){0, 0, 0, 0, 0, 0, 0, 0};
        }
      }
    }
    __syncthreads();

    f32x4 acc[8][2];
#pragma unroll
    for (int nt = 0; nt < 8; ++nt)
#pragma unroll
      for (int vv = 0; vv < 2; ++vv) acc[nt][vv] = (f32x4){0.f, 0.f, 0.f, 0.f};

#pragma unroll
    for (int ks = 0; ks < 4; ++ks) {
      bf16x8 bw[8];
#pragma unroll
      for (int nt = 0; nt < 8; ++nt)
        bw[nt] = *(const bf16x8*)&sWf[(ks * 8 + nt) * 512 + lane * 8];
#pragma unroll
      for (int nt = 0; nt < 8; ++nt)
#pragma unroll
        for (int vv = 0; vv < 2; ++vv)
          acc[nt][vv] = __builtin_amdgcn_mfma_f32_16x16x32_bf16(af[ks][vv], bw[nt], acc[nt][vv], 0, 0, 0);
    }

#pragma unroll
    for (int nt = 0; nt < 8; ++nt)
#pragma unroll
      for (int vv = 0; vv < 2; ++vv)
#pragma unroll
        for (int r = 0; r < 4; ++r) {
          int m = m0 + w * 32 + vv * 16 + lq * 4 + r;
          hb16[(size_t)m * HH + nt * 16 + lr] = f2bf(acc[nt][vv][r]);
        }
  } else {
    __shared__ float red[256];
    const int c = blockIdx.x - NHM;
    if (t < 8) s1[t * KS + c] = 0.f;
    if (t >= 8 && t < 16) s2[(t - 8) * KS + c] = 0.f;
    if (c < 32) accum[c * 256 + t] = 0.f;   // zero all 8 replicas (8*1024)
    float s = 0.f;
    for (int b = t; b < BB; b += 256) s += __expf(cw0[(size_t)b * KS + c]);
    red[t] = s;
    __syncthreads();
    for (int o = 128; o > 0; o >>= 1) {
      if (t < o) red[t] += red[t + o];
      __syncthreads();
    }
    if (t == 0) cm[c] = red[0];
  }
}

// ---------------- routing: per-batch step (h LDS-staged, bf16) ------------
// R6 form (measured best). 3 separate launches = the grid barrier.
// Launch 1 carries CONVB extra blocks doing the emb->bf16 conv.
__global__ __launch_bounds__(256) void k_route(const float* __restrict__ cwsrc,
                                               float* __restrict__ cwdst,
                                               const ushort* __restrict__ hb16,
                                               const float* __restrict__ csum,
                                               int nslots,
                                               const float* __restrict__ mask,
                                               int last,
                                               float* __restrict__ out_ue,
                                               const float* __restrict__ emb,
                                               const int* __restrict__ item,
                                               ushort* __restrict__ bestb,
                                               float* __restrict__ csnext,
                                               float* __restrict__ si,
                                               ushort* __restrict__ embb) {
  const int t = threadIdx.x;
  if (blockIdx.x >= BB) {
    // emb -> bf16 (zero-pad tail to VPAD rows), grid-strided (route1 only)
    const size_t stride = (size_t)CONVB * 256 * 4;
    for (size_t i = ((size_t)(blockIdx.x - BB) * 256 + t) * 4;
         i < (size_t)VPAD * HH; i += stride) {
      ushort4 o;
      if (i < (size_t)VV * HH) {
        float4 v = *(const float4*)&emb[i];
        o = make_ushort4(f2bf(v.x), f2bf(v.y), f2bf(v.z), f2bf(v.w));
      } else {
        o = make_ushort4(0, 0, 0, 0);
      }
      *(ushort4*)&embb[i] = o;
    }
    return;
  }

  __shared__ ushort shT[128 * SSP];   // [col][s] transposed h, 13 KB
  __shared__ float swl[KS];
  __shared__ float c32p[256];
  __shared__ float c32[128];
  __shared__ float csq[128];
  __shared__ float ie4r[32];
  __shared__ float ie4z[32];
  __shared__ float fac[4];
  __shared__ float cosk[4];
  __shared__ float cosr[4];
  __shared__ int kb;
  const int b = blockIdx.x;

  for (int p = t; p < (SS * HH) / 4; p += 256) {
    int flat = 4 * p;
    int s = flat >> 7, col = flat & 127;
    ushort4 v = *(const ushort4*)&hb16[(size_t)b * SS * HH + flat];
    shT[(col + 0) * SSP + s] = v.x;
    shT[(col + 1) * SSP + s] = v.y;
    shT[(col + 2) * SSP + s] = v.z;
    shT[(col + 3) * SSP + s] = v.w;
  }
  if (t < KS) {
    float den = 0.f;
    for (int g2 = 0; g2 < nslots; ++g2) den += csum[g2 * KS + t];
    float v = __expf(cwsrc[(size_t)b * KS + t]) / den;
    if (mask[b * SS + (t % SS)] == 0.0f) v = 0.0f;
    swl[t] = v;
  }
  __syncthreads();

  {  // c32: col = t&127, s-half = t>>7 (25 each)
    int col = t & 127;
    int half = t >> 7;
    int k = col >> 5;
    float acc = 0.f;
    const float* swk = &swl[k * SS + half * 25];
    const ushort* hc = &shT[col * SSP + half * 25];
    for (int s = 0; s < 25; ++s) acc += swk[s] * bf2f(hc[s]);
    c32p[t] = acc;
  }
  __syncthreads();
  if (t < 128) c32[t] = c32p[t] + c32p[t + 128];
  __syncthreads();
  if (t < 4) {
    float nrm = 0.f;
#pragma unroll
    for (int j = 0; j < 32; ++j) { float c = c32[32 * t + j]; nrm += c * c; }
    nrm *= 4.0f;
    fac[t] = nrm / (1.0f + nrm) / sqrtf(nrm + 1e-9f);
  }
  __syncthreads();
  if (t < 128) csq[t] = c32[t] * fac[t >> 5];
  __syncthreads();

  if (!last) {
    if (t < KS) {
      int k = t / SS, s = t % SS;
      const float* cq = &csq[32 * k];
      float d = 0.f;
#pragma unroll
      for (int j = 0; j < 32; ++j) d += bf2f(shT[(32 * k + j) * SSP + s]) * cq[j];
      float nv = cwsrc[(size_t)b * KS + t] + 4.0f * d;
      cwdst[(size_t)b * KS + t] = nv;
      atomicAdd(&csnext[(b & 7) * KS + t], __expf(nv));
    }
  } else {
    for (int hh = t; hh < 512; hh += 256) {
      int k = hh >> 7, r = (hh & 127) >> 2;
      out_ue[(size_t)b * 512 + hh] = csq[32 * k + r];
    }
    if (t < 32) {
      int idx = item[b];
      const float* e = emb + (size_t)idx * HH + 4 * t;
      float v = e[0] + e[1] + e[2] + e[3];   // raw emb row (scores use raw emb)
      ie4r[t] = v;
      ie4z[t] = (idx == 0) ? 0.f : v;        // zeroed lookup (cos path)
    }
    __syncthreads();
    if (t < 4) {
      float cz = 0.f, cr = 0.f;
#pragma unroll
      for (int j = 0; j < 32; ++j) {
        cz += csq[32 * t + j] * ie4z[j];
        cr += csq[32 * t + j] * ie4r[j];
      }
      cosk[t] = cz; cosr[t] = cr;
    }
    __syncthreads();
    if (t == 0) {
      int kbest = 0; float bv = cosk[0];
#pragma unroll
      for (int k = 1; k < 4; ++k) if (cosk[k] > bv) { bv = cosk[k]; kbest = k; }
      kb = kbest;
      si[b] = cosr[kbest];
    }
    __syncthreads();
    // pre-scale by log2(e): scoring epilogue then uses exp2 (single v_exp_f32)
    if (t < 128) bestb[(size_t)b * HH + t] = f2bf(csq[32 * kb + (t >> 2)] * LOG2E);
  }
}

// ---------------- scoring: v9 = barrier-free 7-tile pipelined chain -------
// Ladder: v1=54.2 -> v5=53.2 (async stage) -> v7=49.0 (2 tiles/drain) ->
// v8 16-wave=66.8 (REGRESSED: 1024-thr barrier couples 16 waves). Per-wave
// lifetime at v7 is ~5.6us vs ~0.8us compute: 85% is the one-shot
// load->drain. v9 removes it: block = 7-tile CHAIN per bt-strip. sB is
// tile-invariant -> staged ONCE (async), ONE barrier; then each wave streams
// 7 tiles with explicit double-buffered A-fragments (afA/afB) — tile i+1's
// 8 loads issue before tile i's MFMA cluster (sched_barrier(0) pins the
// order, the v2/v3 failure), so L2 latency (~0.2us) hides under compute
// (~0.8us/tile). No barrier, no vmcnt(0) in the loop. exp sums accumulate
// across the chain -> one ssm+atomic pass per 7 tiles (WRITE ~7x down).
// Paired-bt accumulators keep live acc at 16 VGPR (vs 64) for occupancy.
__global__ __launch_bounds__(256) void k_score_mfma(const ushort* __restrict__ bestb,
                                                    const ushort* __restrict__ embb,
                                                    float* __restrict__ accum) {
  const int lin = blockIdx.x;
  const int xcd = lin & 7;          // same-xcd blocks share an embb slice (L2)
  const int j = lin >> 3;           // 0..111
  const int bt8 = j & 7;            // b strip (128 rows)
  const int chunk = j >> 3;         // 0..13
  const int vt0 = xcd * 98 + chunk * SVPB;

  __shared__ __align__(16) ushort sB[32 * 512];   // 32 KB
  __shared__ float ssm[128][4];
  const int t = threadIdx.x;
  const int w = t >> 6;
  const int lane = t & 63;
  const int lr = lane & 15;
  const int lq = lane >> 4;
  const int b0 = bt8 * 128;

  // stage bestb strip direct to LDS (async, once per chain)
#pragma unroll
  for (int it = 0; it < 8; ++it) {
    int ch = w + it * 4;
    int ks = ch >> 3, bt = ch & 7;
    const ushort* src = &bestb[(size_t)(b0 + bt * 16 + lr) * HH + ks * 32 + lq * 8];
    __builtin_amdgcn_global_load_lds(
        (const __attribute__((address_space(1))) unsigned int*)src,
        (__attribute__((address_space(3))) unsigned int*)&sB[ch * 512 + lane * 8],
        16, 0, 0);
  }

  // per-wave A base; tile i at abase + i*128*HH
  const ushort* abase = &embb[(size_t)(vt0 * 128 + w * 32 + lr) * HH + lq * 8];

  bf16x8 afA[4][2], afB[4][2];
#pragma unroll
  for (int ks = 0; ks < 4; ++ks)
#pragma unroll
    for (int vv = 0; vv < 2; ++vv)
      afA[ks][vv] = *(const bf16x8*)&abase[(size_t)vv * 16 * HH + ks * 32];

  float sacc[8];
#pragma unroll
  for (int bt = 0; bt < 8; ++bt) sacc[bt] = 0.f;

  __syncthreads();   // the ONLY pre-compute barrier (sB + afA drain)

  auto tile_body = [&](const bf16x8 (&cur)[4][2], bf16x8 (&nxt)[4][2], int i) {
    if (i + 1 < SVPB) {   // prefetch tile i+1's A-fragments
      const ushort* nb = abase + (size_t)(i + 1) * 128 * HH;
#pragma unroll
      for (int ks = 0; ks < 4; ++ks)
#pragma unroll
        for (int vv = 0; vv < 2; ++vv)
          nxt[ks][vv] = *(const bf16x8*)&nb[(size_t)vv * 16 * HH + ks * 32];
    }
    __builtin_amdgcn_sched_barrier(0);   // pin prefetch issue before MFMAs
#pragma unroll
    for (int btp = 0; btp < 4; ++btp) {
      f32x4 acc[2][2];
#pragma unroll
      for (int x = 0; x < 2; ++x)
#pragma unroll
        for (int vv = 0; vv < 2; ++vv) acc[x][vv] = (f32x4){0.f, 0.f, 0.f, 0.f};
#pragma unroll
      for (int ks = 0; ks < 4; ++ks) {
        bf16x8 bw0 = *(const bf16x8*)&sB[(ks * 8 + btp * 2 + 0) * 512 + lane * 8];
        bf16x8 bw1 = *(const bf16x8*)&sB[(ks * 8 + btp * 2 + 1) * 512 + lane * 8];
#pragma unroll
        for (int vv = 0; vv < 2; ++vv) {
          acc[0][vv] = __builtin_amdgcn_mfma_f32_16x16x32_bf16(cur[ks][vv], bw0, acc[0][vv], 0, 0, 0);
          acc[1][vv] = __builtin_amdgcn_mfma_f32_16x16x32_bf16(cur[ks][vv], bw1, acc[1][vv], 0, 0, 0);
        }
      }
#pragma unroll
      for (int x = 0; x < 2; ++x) {
        float e[8];
#pragma unroll
        for (int vv = 0; vv < 2; ++vv)
#pragma unroll
          for (int r = 0; r < 4; ++r)
            e[vv * 4 + r] = __builtin_amdgcn_exp2f(acc[x][vv][r]);
#pragma unroll
        for (int o = 4; o > 0; o >>= 1)
#pragma unroll
          for (int q = 0; q < 8; ++q)
            if (q < o) e[q] += e[q + o];
        sacc[btp * 2 + x] += e[0];
      }
    }
  };

  tile_body(afA, afB, 0);
  tile_body(afB, afA, 1);
  tile_body(afA, afB, 2);
  tile_body(afB, afA, 3);
  tile_body(afA, afB, 4);
  tile_body(afB, afA, 5);
  tile_body(afA, afB, 6);

  // chain epilogue: reduce over lq groups, then across the 4 waves
#pragma unroll
  for (int bt = 0; bt < 8; ++bt) {
    float s = sacc[bt];
    s += __shfl_xor(s, 16);
    s += __shfl_xor(s, 32);
    if (lq == 0) ssm[bt * 16 + lr][w] = s;
  }
  __syncthreads();
  if (t < 128) {
    float s = ssm[t][0] + ssm[t][1] + ssm[t][2] + ssm[t][3];
    atomicAdd(&accum[(size_t)(lin & 7) * BB + b0 + t], s);
  }
}

// ---------------- final loss: one block -----------------------------------
__global__ __launch_bounds__(256) void k_loss(const float* __restrict__ accum,
                                              const float* __restrict__ si,
                                              float* __restrict__ outloss) {
  __shared__ float red[256];
  const int t = threadIdx.x;
  float s = 0.f;
  for (int b = t; b < BB; b += 256) {
    float a = 0.f;
#pragma unroll
    for (int r = 0; r < 8; ++r) a += accum[(size_t)r * BB + b];
    s += logf(a - NPAD_ALL) - si[b];   // no max: scores ~[-0.5,0.5]
  }
  red[t] = s;
  __syncthreads();
  for (int o = 128; o > 0; o >>= 1) {
    if (t < o) red[t] += red[t + o];
    __syncthreads();
  }
  if (t == 0) outloss[0] = red[0] / (float)BB;
}

extern "C" void kernel_launch(void* const* d_in, const int* in_sizes, int n_in,
                              void* d_out, int out_size, void* d_ws, size_t ws_size,
                              hipStream_t stream) {
  const int*   item_seq = (const int*)d_in[0];
  const float* mask     = (const float*)d_in[1];
  const int*   item     = (const int*)d_in[2];
  const float* emb      = (const float*)d_in[3];
  const float* W        = (const float*)d_in[4];
  const float* cw0      = (const float*)d_in[5];
  float* out = (float*)d_out;
  float* outloss = out + (size_t)BB * KK * HH;

  float* ws = (float*)d_ws;
  float* cm    = ws;                                 // KS (rounded 256)
  float* s1    = cm + 256;                           // 8*200
  float* s2    = s1 + 8 * KS;                        // 8*200
  float* si    = s2 + 8 * KS;                        // B
  float* accum = si + BB;                            // 8*B (replicated)
  float* cw    = accum + 8 * BB;                     // B*K*S
  ushort* hb16  = (ushort*)(cw + (size_t)BB * KS);   // B*S*H bf16
  ushort* embb  = hb16 + (size_t)BB * SS * HH;       // VPAD*H bf16
  ushort* bestb = embb + (size_t)VPAD * HH;          // B*H bf16

  k_pre<<<dim3(NHM + KS), 256, 0, stream>>>(emb, cw0, cm, s1, s2, accum,
                                            item_seq, W, hb16);

  k_route<<<dim3(BB + CONVB), 256, 0, stream>>>(cw0, cw, hb16, cm, 1, mask, 0, out, emb, item, bestb, s1, si, embb);
  k_route<<<dim3(BB), 256, 0, stream>>>(cw, cw, hb16, s1, 8, mask, 0, out, emb, item, bestb, s2, si, embb);
  k_route<<<dim3(BB), 256, 0, stream>>>(cw, cw, hb16, s2, 8, mask, 1, out, emb, item, bestb, s1, si, embb);

  k_score_mfma<<<dim3(SGRID), 256, 0, stream>>>(bestb, embb, accum);
  k_loss<<<dim3(1), 256, 0, stream>>>(accum, si, outloss);
}

// Round 12
// 192.656 us; speedup vs baseline: 1.0697x; 1.0200x over previous
//
#include <hip/hip_runtime.h>
#include <math.h>

#define BB 1024
#define SS 50
#define SSP 51          // padded LDS row stride for shT
#define HH 128
#define KK 4
#define VV 100000
#define NVT8 784        // v-tiles padded: 98/XCD (49 pairs)
#define VPAD (NVT8*128) // 100352 zero-padded emb rows
#define KS (KK*SS)      // 200
#define NHM 400         // h-MFMA blocks (128 rows each)
#define NPAD_ALL 352.0f // zero pad rows ALL scored: VPAD-VV, exp(0)=1 each
#define CONVB 1024      // conv blocks riding on EACH route launch (1/3 slice)
#define CSLICE 4284416  // ceil(VPAD*HH/3 / 4096)*4096 elements per slice
#define LOG2E 1.44269504f
#define SGRID ((NVT8/2)*8)  // 3136: 8-wave block, TWO 128v x 128b tiles/block

typedef __attribute__((ext_vector_type(8))) short bf16x8;
typedef __attribute__((ext_vector_type(4))) float f32x4;

__device__ __forceinline__ ushort f2bf(float x) {
  unsigned u = __float_as_uint(x);
  unsigned r = u + 0x7FFF + ((u >> 16) & 1);   // round-to-nearest-even
  return (ushort)(r >> 16);
}
__device__ __forceinline__ float bf2f(ushort u) {
  return __uint_as_float(((unsigned)u) << 16);
}
__device__ __forceinline__ bf16x8 cvt8(float4 a, float4 b) {
  bf16x8 r;
  r[0] = (short)f2bf(a.x); r[1] = (short)f2bf(a.y);
  r[2] = (short)f2bf(a.z); r[3] = (short)f2bf(a.w);
  r[4] = (short)f2bf(b.x); r[5] = (short)f2bf(b.y);
  r[6] = (short)f2bf(b.z); r[7] = (short)f2bf(b.w);
  return r;
}

// ---- fused pre-pass ------------------------------------------------------
// blocks [0,NHM): h = seq_emb @ W^T via bf16 MFMA -> hb16
// blocks [NHM,NHM+KS): cw0 column exp-sums + zero s1/s2/accum (8 replicas)
__global__ __launch_bounds__(256) void k_pre(const float* __restrict__ emb,
                                             const float* __restrict__ cw0,
                                             float* __restrict__ cm,
                                             float* __restrict__ s1,
                                             float* __restrict__ s2,
                                             float* __restrict__ accum,
                                             const int* __restrict__ item_seq,
                                             const float* __restrict__ W,
                                             ushort* __restrict__ hb16) {
  const int t = threadIdx.x;
  if (blockIdx.x < NHM) {
    __shared__ __align__(16) ushort sWf[32 * 512];   // W bf16 fragments, 32 KB
    const int w = t >> 6;
    const int lane = t & 63;
    const int lr = lane & 15;
    const int lq = lane >> 4;
    const int m0 = blockIdx.x * 128;

#pragma unroll
    for (int it = 0; it < 8; ++it) {
      int pos = t + it * 256;
      int ch = pos >> 6, l = pos & 63;
      int n = (ch & 7) * 16 + (l & 15);
      int k0 = (ch >> 3) * 32 + (l >> 4) * 8;
      float4 a = *(const float4*)&W[n * HH + k0];
      float4 b = *(const float4*)&W[n * HH + k0 + 4];
      *(bf16x8*)&sWf[ch * 512 + l * 8] = cvt8(a, b);
    }

    bf16x8 af[4][2];
#pragma unroll
    for (int vv = 0; vv < 2; ++vv) {
      int m = m0 + w * 32 + vv * 16 + lr;
      int idx = item_seq[m];
#pragma unroll
      for (int ks = 0; ks < 4; ++ks) {
        if (idx != 0) {
          float4 a = *(const float4*)&emb[(size_t)idx * HH + ks * 32 + lq * 8];
          float4 b = *(const float4*)&emb[(size_t)idx * HH + ks * 32 + lq * 8 + 4];
          af[ks][vv] = cvt8(a, b);
        } else {
          af[ks][vv] = (bf16x8){0, 0, 0, 0, 0, 0, 0, 0};
        }
      }
    }
    __syncthreads();

    f32x4 acc[8][2];
#pragma unroll
    for (int nt = 0; nt < 8; ++nt)
#pragma unroll
      for (int vv = 0; vv < 2; ++vv) acc[nt][vv] = (f32x4){0.f, 0.f, 0.f, 0.f};

#pragma unroll
    for (int ks = 0; ks < 4; ++ks) {
      bf16x8 bw[8];
#pragma unroll
      for (int nt = 0; nt < 8; ++nt)
        bw[nt] = *(const bf16x8*)&sWf[(ks * 8 + nt) * 512 + lane * 8];
#pragma unroll
      for (int nt = 0; nt < 8; ++nt)
#pragma unroll
        for (int vv = 0; vv < 2; ++vv)
          acc[nt][vv] = __builtin_amdgcn_mfma_f32_16x16x32_bf16(af[ks][vv], bw[nt], acc[nt][vv], 0, 0, 0);
    }

#pragma unroll
    for (int nt = 0; nt < 8; ++nt)
#pragma unroll
      for (int vv = 0; vv < 2; ++vv)
#pragma unroll
        for (int r = 0; r < 4; ++r) {
          int m = m0 + w * 32 + vv * 16 + lq * 4 + r;
          hb16[(size_t)m * HH + nt * 16 + lr] = f2bf(acc[nt][vv][r]);
        }
  } else {
    __shared__ float red[256];
    const int c = blockIdx.x - NHM;
    if (t < 8) s1[t * KS + c] = 0.f;
    if (t >= 8 && t < 16) s2[(t - 8) * KS + c] = 0.f;
    if (c < 32) accum[c * 256 + t] = 0.f;   // zero all 8 replicas (8*1024)
    float s = 0.f;
    for (int b = t; b < BB; b += 256) s += __expf(cw0[(size_t)b * KS + c]);
    red[t] = s;
    __syncthreads();
    for (int o = 128; o > 0; o >>= 1) {
      if (t < o) red[t] += red[t + o];
      __syncthreads();
    }
    if (t == 0) cm[c] = red[0];
  }
}

// ---------------- routing: per-batch step (h LDS-staged, bf16) ------------
// R6 form (measured best: per-b blocks, R8's per-(b,k) split refuted).
// NEW in R12: the emb->bf16 conv is split into THIRDS across the three
// route launches (convp=0,1,2; CONVB extra blocks each). R6 proved conv
// rides nearly free on a latency-bound route launch, but ALL of it on
// route1 exceeded route1's latency shadow (~77 MB of streaming). ~26 MB
// per launch fits inside each route's shadow. embb is only read by
// k_score (after route3), so slice 2 is ready in time.
__global__ __launch_bounds__(256) void k_route(const float* __restrict__ cwsrc,
                                               float* __restrict__ cwdst,
                                               const ushort* __restrict__ hb16,
                                               const float* __restrict__ csum,
                                               int nslots,
                                               const float* __restrict__ mask,
                                               int last,
                                               float* __restrict__ out_ue,
                                               const float* __restrict__ emb,
                                               const int* __restrict__ item,
                                               ushort* __restrict__ bestb,
                                               float* __restrict__ csnext,
                                               float* __restrict__ si,
                                               ushort* __restrict__ embb,
                                               int convp) {
  const int t = threadIdx.x;
  if (blockIdx.x >= BB) {
    // emb -> bf16 slice convp (zero-pad tail to VPAD rows), grid-strided
    const size_t beg = (size_t)convp * CSLICE;
    size_t end = beg + CSLICE;
    if (end > (size_t)VPAD * HH) end = (size_t)VPAD * HH;
    const size_t stride = (size_t)CONVB * 256 * 4;
    for (size_t i = beg + ((size_t)(blockIdx.x - BB) * 256 + t) * 4;
         i < end; i += stride) {
      ushort4 o;
      if (i < (size_t)VV * HH) {
        float4 v = *(const float4*)&emb[i];
        o = make_ushort4(f2bf(v.x), f2bf(v.y), f2bf(v.z), f2bf(v.w));
      } else {
        o = make_ushort4(0, 0, 0, 0);
      }
      *(ushort4*)&embb[i] = o;
    }
    return;
  }

  __shared__ ushort shT[128 * SSP];   // [col][s] transposed h, 13 KB
  __shared__ float swl[KS];
  __shared__ float c32p[256];
  __shared__ float c32[128];
  __shared__ float csq[128];
  __shared__ float ie4r[32];
  __shared__ float ie4z[32];
  __shared__ float fac[4];
  __shared__ float cosk[4];
  __shared__ float cosr[4];
  __shared__ int kb;
  const int b = blockIdx.x;

  for (int p = t; p < (SS * HH) / 4; p += 256) {
    int flat = 4 * p;
    int s = flat >> 7, col = flat & 127;
    ushort4 v = *(const ushort4*)&hb16[(size_t)b * SS * HH + flat];
    shT[(col + 0) * SSP + s] = v.x;
    shT[(col + 1) * SSP + s] = v.y;
    shT[(col + 2) * SSP + s] = v.z;
    shT[(col + 3) * SSP + s] = v.w;
  }
  if (t < KS) {
    float den = 0.f;
    for (int g2 = 0; g2 < nslots; ++g2) den += csum[g2 * KS + t];
    float v = __expf(cwsrc[(size_t)b * KS + t]) / den;
    if (mask[b * SS + (t % SS)] == 0.0f) v = 0.0f;
    swl[t] = v;
  }
  __syncthreads();

  {  // c32: col = t&127, s-half = t>>7 (25 each)
    int col = t & 127;
    int half = t >> 7;
    int k = col >> 5;
    float acc = 0.f;
    const float* swk = &swl[k * SS + half * 25];
    const ushort* hc = &shT[col * SSP + half * 25];
    for (int s = 0; s < 25; ++s) acc += swk[s] * bf2f(hc[s]);
    c32p[t] = acc;
  }
  __syncthreads();
  if (t < 128) c32[t] = c32p[t] + c32p[t + 128];
  __syncthreads();
  if (t < 4) {
    float nrm = 0.f;
#pragma unroll
    for (int j = 0; j < 32; ++j) { float c = c32[32 * t + j]; nrm += c * c; }
    nrm *= 4.0f;
    fac[t] = nrm / (1.0f + nrm) / sqrtf(nrm + 1e-9f);
  }
  __syncthreads();
  if (t < 128) csq[t] = c32[t] * fac[t >> 5];
  __syncthreads();

  if (!last) {
    if (t < KS) {
      int k = t / SS, s = t % SS;
      const float* cq = &csq[32 * k];
      float d = 0.f;
#pragma unroll
      for (int j = 0; j < 32; ++j) d += bf2f(shT[(32 * k + j) * SSP + s]) * cq[j];
      float nv = cwsrc[(size_t)b * KS + t] + 4.0f * d;
      cwdst[(size_t)b * KS + t] = nv;
      atomicAdd(&csnext[(b & 7) * KS + t], __expf(nv));
    }
  } else {
    for (int hh = t; hh < 512; hh += 256) {
      int k = hh >> 7, r = (hh & 127) >> 2;
      out_ue[(size_t)b * 512 + hh] = csq[32 * k + r];
    }
    if (t < 32) {
      int idx = item[b];
      const float* e = emb + (size_t)idx * HH + 4 * t;
      float v = e[0] + e[1] + e[2] + e[3];   // raw emb row (scores use raw emb)
      ie4r[t] = v;
      ie4z[t] = (idx == 0) ? 0.f : v;        // zeroed lookup (cos path)
    }
    __syncthreads();
    if (t < 4) {
      float cz = 0.f, cr = 0.f;
#pragma unroll
      for (int j = 0; j < 32; ++j) {
        cz += csq[32 * t + j] * ie4z[j];
        cr += csq[32 * t + j] * ie4r[j];
      }
      cosk[t] = cz; cosr[t] = cr;
    }
    __syncthreads();
    if (t == 0) {
      int kbest = 0; float bv = cosk[0];
#pragma unroll
      for (int k = 1; k < 4; ++k) if (cosk[k] > bv) { bv = cosk[k]; kbest = k; }
      kb = kbest;
      si[b] = cosr[kbest];
    }
    __syncthreads();
    // pre-scale by log2(e): scoring epilogue then uses exp2 (single v_exp_f32)
    if (t < 128) bestb[(size_t)b * HH + t] = f2bf(csq[32 * kb + (t >> 2)] * LOG2E);
  }
}

// ---------------- scoring: v7 (measured best, 49.0 us) --------------------
// Final k_score ladder: v1=54.2 (1 tile/4w) -> v5=53.2 (async stage) ->
// v7=49.0 (2 tiles/8w, one drain) <- BEST; v8 4-tile/16w=66.8; v9 7-tile
// pipelined chain=53.7 (VGPR 236 -> occ 9%). The amortization<->residency
// tradeoff is fully mapped; v7 is the floor. Geometry PINNED.
__global__ __launch_bounds__(512) void k_score_mfma(const ushort* __restrict__ bestb,
                                                    const ushort* __restrict__ embb,
                                                    float* __restrict__ accum) {
  const int lin = blockIdx.x;
  const int xcd = lin & 7;          // same-xcd blocks share an embb slice (L2)
  const int g = lin >> 3;           // 0..391
  const int bt8 = g & 7;            // b strip (128 rows)
  const int vt0 = xcd * 98 + (g >> 3) * 2;   // pair base, g>>3 in 0..48

  __shared__ __align__(16) ushort sB[32 * 512];   // 32 KB
  __shared__ float ssm[128][8];
  const int t = threadIdx.x;
  const int w = t >> 6;             // 0..7
  const int lane = t & 63;
  const int lr = lane & 15;
  const int lq = lane >> 4;
  const int b0 = bt8 * 128;
  const int tile = w >> 2;          // which v-tile of the pair
  const int ws = w & 3;             // wave-sub within tile
  const int v0 = (vt0 + tile) * 128 + ws * 32;

  // emb fragments (per-wave unique), hoisted: 32 VGPRs in flight
  bf16x8 af[4][2];
#pragma unroll
  for (int ks = 0; ks < 4; ++ks)
#pragma unroll
    for (int vv = 0; vv < 2; ++vv)
      af[ks][vv] = *(const bf16x8*)&embb[(size_t)(v0 + vv * 16 + lr) * HH + ks * 32 + lq * 8];

  // stage bestb strip direct to LDS (async): 32 chunks over 8 waves.
#pragma unroll
  for (int it = 0; it < 4; ++it) {
    int ch = w + it * 8;
    int ks = ch >> 3, bt = ch & 7;
    const ushort* src = &bestb[(size_t)(b0 + bt * 16 + lr) * HH + ks * 32 + lq * 8];
    __builtin_amdgcn_global_load_lds(
        (const __attribute__((address_space(1))) unsigned int*)src,
        (__attribute__((address_space(3))) unsigned int*)&sB[ch * 512 + lane * 8],
        16, 0, 0);
  }

  f32x4 acc[8][2];
#pragma unroll
  for (int bt = 0; bt < 8; ++bt)
#pragma unroll
    for (int vv = 0; vv < 2; ++vv) acc[bt][vv] = (f32x4){0.f, 0.f, 0.f, 0.f};

  __syncthreads();   // one vmcnt drain for 2 tiles' worth of compute

  bf16x8 bcur[8];
#pragma unroll
  for (int bt = 0; bt < 8; ++bt)
    bcur[bt] = *(const bf16x8*)&sB[bt * 512 + lane * 8];

#pragma unroll
  for (int ks = 0; ks < 4; ++ks) {
    bf16x8 bnxt[8];
    if (ks < 3) {
#pragma unroll
      for (int bt = 0; bt < 8; ++bt)
        bnxt[bt] = *(const bf16x8*)&sB[((ks + 1) * 8 + bt) * 512 + lane * 8];
    }
#pragma unroll
    for (int bt = 0; bt < 8; ++bt)
#pragma unroll
      for (int vv = 0; vv < 2; ++vv)
        acc[bt][vv] = __builtin_amdgcn_mfma_f32_16x16x32_bf16(af[ks][vv], bcur[bt], acc[bt][vv], 0, 0, 0);
    if (ks < 3) {
#pragma unroll
      for (int bt = 0; bt < 8; ++bt) bcur[bt] = bnxt[bt];
    }
  }

  // epilogue: scores pre-scaled by log2(e) -> single v_exp_f32 each
#pragma unroll
  for (int bt = 0; bt < 8; ++bt) {
    float e[8];
#pragma unroll
    for (int vv = 0; vv < 2; ++vv)
#pragma unroll
      for (int r = 0; r < 4; ++r)
        e[vv * 4 + r] = __builtin_amdgcn_exp2f(acc[bt][vv][r]);
#pragma unroll
    for (int o = 4; o > 0; o >>= 1)
#pragma unroll
      for (int j = 0; j < 8; ++j)
        if (j < o) e[j] += e[j + o];
    float s = e[0];
    s += __shfl_xor(s, 16);
    s += __shfl_xor(s, 32);
    if (lq == 0) ssm[bt * 16 + lr][w] = s;
  }
  __syncthreads();
  if (t < 128) {
    float s = 0.f;
#pragma unroll
    for (int r = 0; r < 8; ++r) s += ssm[t][r];
    atomicAdd(&accum[(size_t)(lin & 7) * BB + b0 + t], s);
  }
}

// ---------------- final loss: one block -----------------------------------
__global__ __launch_bounds__(256) void k_loss(const float* __restrict__ accum,
                                              const float* __restrict__ si,
                                              float* __restrict__ outloss) {
  __shared__ float red[256];
  const int t = threadIdx.x;
  float s = 0.f;
  for (int b = t; b < BB; b += 256) {
    float a = 0.f;
#pragma unroll
    for (int r = 0; r < 8; ++r) a += accum[(size_t)r * BB + b];
    s += logf(a - NPAD_ALL) - si[b];   // no max: scores ~[-0.5,0.5]
  }
  red[t] = s;
  __syncthreads();
  for (int o = 128; o > 0; o >>= 1) {
    if (t < o) red[t] += red[t + o];
    __syncthreads();
  }
  if (t == 0) outloss[0] = red[0] / (float)BB;
}

extern "C" void kernel_launch(void* const* d_in, const int* in_sizes, int n_in,
                              void* d_out, int out_size, void* d_ws, size_t ws_size,
                              hipStream_t stream) {
  const int*   item_seq = (const int*)d_in[0];
  const float* mask     = (const float*)d_in[1];
  const int*   item     = (const int*)d_in[2];
  const float* emb      = (const float*)d_in[3];
  const float* W        = (const float*)d_in[4];
  const float* cw0      = (const float*)d_in[5];
  float* out = (float*)d_out;
  float* outloss = out + (size_t)BB * KK * HH;

  float* ws = (float*)d_ws;
  float* cm    = ws;                                 // KS (rounded 256)
  float* s1    = cm + 256;                           // 8*200
  float* s2    = s1 + 8 * KS;                        // 8*200
  float* si    = s2 + 8 * KS;                        // B
  float* accum = si + BB;                            // 8*B (replicated)
  float* cw    = accum + 8 * BB;                     // B*K*S
  ushort* hb16  = (ushort*)(cw + (size_t)BB * KS);   // B*S*H bf16
  ushort* embb  = hb16 + (size_t)BB * SS * HH;       // VPAD*H bf16
  ushort* bestb = embb + (size_t)VPAD * HH;          // B*H bf16

  k_pre<<<dim3(NHM + KS), 256, 0, stream>>>(emb, cw0, cm, s1, s2, accum,
                                            item_seq, W, hb16);

  k_route<<<dim3(BB + CONVB), 256, 0, stream>>>(cw0, cw, hb16, cm, 1, mask, 0, out, emb, item, bestb, s1, si, embb, 0);
  k_route<<<dim3(BB + CONVB), 256, 0, stream>>>(cw, cw, hb16, s1, 8, mask, 0, out, emb, item, bestb, s2, si, embb, 1);
  k_route<<<dim3(BB + CONVB), 256, 0, stream>>>(cw, cw, hb16, s2, 8, mask, 1, out, emb, item, bestb, s1, si, embb, 2);

  k_score_mfma<<<dim3(SGRID), 512, 0, stream>>>(bestb, embb, accum);
  k_loss<<<dim3(1), 256, 0, stream>>>(accum, si, outloss);
}